// Round 12
// baseline (83.170 us; speedup 1.0000x reference)
//
#include <hip/hip_runtime.h>
#include <hip/hip_bf16.h>

// Quantizer (VQ-VAE): inputs [32,2048,256] f32, embed [1024,256] f32.
// out = (quantized [32,2048,256] f32, latent_loss scalar f32) concatenated.
//
// Round-12: round-11 INT8 MFMA argmin + PREFETCH DEPTH 3 (4 rotating B
// buffers; round-11's depth-1 ping-pong left each group ~100-200 cyc short
// of L2 latency -> 60% of argmin wall was vmcnt stall).
//   - e scaled by SE=1024*127 (exact range fit), x by SX=28 (clip ~5e-6)
//   - integer dot exact; key = ((dot+ct)<<10)+(1023-code): exact argmin,
//     lowest-index ties; ct = round(-0.5*||e||^2*SX*SE) in MFMA C-init
//   - loss via sv = (key>>10)/(SX*SE): ||x-e||^2 = ||x||^2 - 2*sv
//
//   prep_kernel   : embed -> i8 FRAGMENT-MAJOR pack + ct_int per code
//   argmin_kernel : 32 rows/wave, full codebook, grid 2048 (2 waves/SIMD);
//                   A i8 in regs a[2][4]; B via 4-buffer depth-3 rotation
//   gather_kernel : q[r] = ew[codes[r]] (1 KB contiguous nt-store per row)
//   loss_kernel   : 1.25 * [sum(x^2) - 2*sum(sv)] / (N*D)

#define DIM     256
#define M_ROWS  65536
#define NCODES  1024
#define SX      28.0f
#define SE      130048.0f        // 1024 * 127

using f32x4  = __attribute__((ext_vector_type(4))) float;
using i32x4  = __attribute__((ext_vector_type(4))) int;

__device__ inline int q8(float f, float s) {
  float v = fminf(fmaxf(f * s, -127.0f), 127.0f);
  return (int)rintf(v);
}

// ---------------------------------------------------------------- prep
// Fragment-major i8 codebook for 16x16x64: group g = codes [g*16,g*16+16),
// k-frag kk covers k=[kk*64,kk*64+64). Lane l holds code g*16+(l&15),
// k = kk*64+(l>>4)*16..+16 (16 B). Frag f = g*4+kk is 1 KB contiguous.
__global__ __launch_bounds__(64) void prep_kernel(const float* __restrict__ ew,
                                                  char* __restrict__ ebf,
                                                  int* __restrict__ ct_int) {
  const int c = blockIdx.x;
  const int t = threadIdx.x;            // handles k = 4t .. 4t+3
  f32x4 v = *((const f32x4*)(ew + (size_t)c * DIM) + t);
  int p = (q8(v[0], SE) & 255) | ((q8(v[1], SE) & 255) << 8)
        | ((q8(v[2], SE) & 255) << 16) | ((q8(v[3], SE) & 255) << 24);
  int frag = (c >> 4) * 4 + (t >> 4);           // kk = t>>4
  int lhi  = (t >> 2) & 3;                      // k-sub within frag
  int addr = frag * 1024 + (lhi * 16 + (c & 15)) * 16 + (t & 3) * 4;
  *(int*)(ebf + addr) = p;
  float ss = v[0] * v[0] + v[1] * v[1] + v[2] * v[2] + v[3] * v[3];
#pragma unroll
  for (int off = 32; off > 0; off >>= 1) ss += __shfl_xor(ss, off, 64);
  if (t == 0) ct_int[c] = (int)rintf(-0.5f * ss * (SX * SE));
}

// ---------------------------------------------------------------- argmin
// One 16-code group: 8 MFMA (i8, K=64) with C-init = ct, then
// key = (acc<<10) + (1023-code) folded by integer max.
#define COMPUTE16(B, CT, GG)                                                    \
  {                                                                             \
    i32x4 acc[2];                                                               \
    acc[0] = i32x4{CT, CT, CT, CT};                                             \
    acc[1] = i32x4{CT, CT, CT, CT};                                             \
    _Pragma("unroll")                                                           \
    for (int kk = 0; kk < 4; ++kk) {                                            \
      acc[0] = __builtin_amdgcn_mfma_i32_16x16x64_i8(a[0][kk], B[kk], acc[0], 0, 0, 0); \
      acc[1] = __builtin_amdgcn_mfma_i32_16x16x64_i8(a[1][kk], B[kk], acc[1], 0, 0, 0); \
    }                                                                           \
    int tr = 1023 - ((GG) * 16 + l15);                                          \
    _Pragma("unroll")                                                           \
    for (int mi = 0; mi < 2; ++mi)                                              \
      _Pragma("unroll")                                                         \
      for (int r = 0; r < 4; ++r) {                                             \
        int key = (int)(((unsigned)acc[mi][r]) << 10) + tr;                     \
        bk[mi][r] = key > bk[mi][r] ? key : bk[mi][r];                          \
      }                                                                         \
  }

// Refill buffer B with group GG's 4 fragments (wave-uniform guard).
#define REFILL(B, CT, GG)                                                       \
  if ((GG) < 64) {                                                              \
    _Pragma("unroll")                                                           \
    for (int f = 0; f < 4; ++f) B[f] = bfr[((GG) * 4 + f) * 64 + lane];         \
    CT = ct_int[(GG) * 16 + l15];                                               \
  }

__global__ __launch_bounds__(64, 1) void argmin_kernel(const float* __restrict__ x,
                                                       const char* __restrict__ ebf,
                                                       const int* __restrict__ ct_int,
                                                       int* __restrict__ out_codes,
                                                       float* __restrict__ partials) {
  const int lane = threadIdx.x;
  const int l15  = lane & 15;
  const int lhi  = lane >> 4;            // 0..3
  const int row0 = blockIdx.x * 32;

  const i32x4* bfr = (const i32x4*)ebf;  // frag f, lane l -> bfr[f*64 + l]

  // ---- issue B prefetch for groups 0..3 FIRST (hides under x-load/q8) ----
  i32x4 b0[4], b1[4], b2[4], b3[4];
  int   ct0, ct1, ct2, ct3;
  REFILL(b0, ct0, 0)
  REFILL(b1, ct1, 1)
  REFILL(b2, ct2, 2)
  REFILL(b3, ct3, 3)

  // ---- X -> registers (i8 frags, same lane->k map as B), x2a in fp32 ----
  float x2a = 0.0f;
  i32x4 a[2][4];
#pragma unroll
  for (int mi = 0; mi < 2; ++mi) {
    const float* xr = x + (size_t)(row0 + mi * 16 + l15) * DIM;
#pragma unroll
    for (int kk = 0; kk < 4; ++kk) {
      const float* ks = xr + kk * 64 + lhi * 16;
      i32x4 pk;
#pragma unroll
      for (int j = 0; j < 4; ++j) {
        f32x4 v = *(const f32x4*)(ks + j * 4);
        x2a += v[0] * v[0] + v[1] * v[1] + v[2] * v[2] + v[3] * v[3];
        pk[j] = (q8(v[0], SX) & 255) | ((q8(v[1], SX) & 255) << 8)
              | ((q8(v[2], SX) & 255) << 16) | ((q8(v[3], SX) & 255) << 24);
      }
      a[mi][kk] = pk;
    }
  }

  int bk[2][4];
#pragma unroll
  for (int i = 0; i < 2; ++i)
#pragma unroll
    for (int r = 0; r < 4; ++r) bk[i][r] = (int)0x80000000;

  // ---- depth-3 rotation: compute b_i(g+i), refill b_i <- g+4+i ----
  for (int g = 0; g < 64; g += 4) {
    COMPUTE16(b0, ct0, g)
    REFILL(b0, ct0, g + 4)
    COMPUTE16(b1, ct1, g + 1)
    REFILL(b1, ct1, g + 5)
    COMPUTE16(b2, ct2, g + 2)
    REFILL(b2, ct2, g + 6)
    COMPUTE16(b3, ct3, g + 3)
    REFILL(b3, ct3, g + 7)
  }

  // ---- reduce int keys over the 16 code-lanes ----
#pragma unroll
  for (int mi = 0; mi < 2; ++mi)
#pragma unroll
    for (int r = 0; r < 4; ++r) {
      int v = bk[mi][r];
#pragma unroll
      for (int off = 1; off < 16; off <<= 1) {
        int o = __shfl_xor(v, off, 64);
        v = o > v ? o : v;
      }
      bk[mi][r] = v;
    }

  float svtot = 0.0f;
  if (l15 == 0) {                        // lanes 0,16,32,48: rows mi*16 + lhi*4 + r
    const float inv_s = 1.0f / (SX * SE);
#pragma unroll
    for (int mi = 0; mi < 2; ++mi)
#pragma unroll
      for (int r = 0; r < 4; ++r) {
        int key = bk[mi][r];
        out_codes[row0 + mi * 16 + lhi * 4 + r] = 1023 - (key & 1023);
        svtot += (float)(key >> 10) * inv_s;   // sv = x.e - 0.5||e||^2
      }
  }
  float red = x2a - 2.0f * svtot;        // partial: sum x^2 - 2*sum sv
#pragma unroll
  for (int off = 1; off < 64; off <<= 1) red += __shfl_xor(red, off, 64);
  if (lane == 0) partials[blockIdx.x] = red;
}

// ---------------------------------------------------------------- gather (pure stream)
// One wave per 8 consecutive rows; each row = 1 KB contiguous (64 lanes x 16 B).
__global__ __launch_bounds__(256) void gather_kernel(const float* __restrict__ ew,
                                                     const int* __restrict__ codes,
                                                     float* __restrict__ qout) {
  const int w    = (blockIdx.x * 256 + threadIdx.x) >> 6;   // 0..8191
  const int lane = threadIdx.x & 63;
  const int base = w * 8;
  int c[8];
#pragma unroll
  for (int i = 0; i < 8; ++i) c[i] = codes[base + i];
#pragma unroll
  for (int i = 0; i < 8; ++i) {
    f32x4 v = *((const f32x4*)(ew + (size_t)c[i] * DIM) + lane);
    __builtin_nontemporal_store(v, ((f32x4*)(qout + (size_t)(base + i) * DIM)) + lane);
  }
}

// ---------------------------------------------------------------- final loss
__global__ __launch_bounds__(256) void loss_kernel(const float* __restrict__ partials,
                                                   float* __restrict__ out_loss) {
  __shared__ double red[256];
  double a = 0.0;
  for (int i = threadIdx.x; i < 2048; i += 256) a += (double)partials[i];
  red[threadIdx.x] = a;
  __syncthreads();
  for (int s = 128; s > 0; s >>= 1) {
    if (threadIdx.x < s) red[threadIdx.x] += red[threadIdx.x + s];
    __syncthreads();
  }
  if (threadIdx.x == 0) out_loss[0] = (float)(1.25 * red[0] / 16777216.0);
}

// ---------------------------------------------------------------- launch
extern "C" void kernel_launch(void* const* d_in, const int* in_sizes, int n_in,
                              void* d_out, int out_size, void* d_ws, size_t ws_size,
                              hipStream_t stream) {
  const float* x  = (const float*)d_in[0];   // inputs [65536,256]
  const float* ew = (const float*)d_in[1];   // embed  [1024,256]
  float* out = (float*)d_out;

  char* ws = (char*)d_ws;
  char*  ebf      = ws;                               // 256 KiB (fragment-major i8)
  int*   ct_int   = (int*)(ws + 262144);              // 4 KiB
  float* partials = (float*)(ws + 266240);            // 8 KiB (2048 waves)
  int*   codes    = (int*)(ws + 274432);              // 256 KiB

  prep_kernel<<<NCODES, 64, 0, stream>>>(ew, ebf, ct_int);
  argmin_kernel<<<M_ROWS / 32, 64, 0, stream>>>(x, ebf, ct_int, codes, partials);
  gather_kernel<<<2048, 256, 0, stream>>>(ew, codes, out);
  loss_kernel<<<1, 256, 0, stream>>>(partials, out + 16777216);
}

// Round 13
// 74.083 us; speedup vs baseline: 1.1227x; 1.1227x over previous
//
#include <hip/hip_runtime.h>
#include <hip/hip_bf16.h>

// Quantizer (VQ-VAE): inputs [32,2048,256] f32, embed [1024,256] f32.
// out = (quantized [32,2048,256] f32, latent_loss scalar f32) concatenated.
//
// Round-13: round-11 INT8 argmin (VGPR 112, depth-1 ping-pong — round-12's
// depth-3 pushed VGPR to 156, crossed the 128 boundary, lost the 2nd
// co-resident wave and regressed) + CODEBOOK SPLIT x2 across BLOCKS:
// block b: rows (b>>1)*32, half b&1 (512 codes). Grid 4096 -> 4 waves/SIMD.
// Halves merged by integer-key max in gather (keys globally comparable).
//   - e scaled by SE=1024*127, x by SX=28 (clip ~5e-6); integer dot exact
//   - key = ((dot+ct)<<10)+(1023-code); ct = round(-0.5||e||^2*SX*SE) in C-init
//   - loss: ||x-e||^2 = ||x||^2 - 2*sv, sv = (key>>10)/(SX*SE)
//
//   prep_kernel   : embed -> i8 FRAGMENT-MAJOR pack + ct_int per code
//   argmin_kernel : keys[row*2+half]; half-0 blocks write sum(x^2) partials
//   gather_kernel : merge keys -> code,sv; q[r] = ew[code] nt-store; sv partials
//   loss_kernel   : 1.25 * [sum(x2) - 2*sum(sv)] / (N*D)

#define DIM     256
#define M_ROWS  65536
#define NCODES  1024
#define SX      28.0f
#define SE      130048.0f        // 1024 * 127

using f32x4  = __attribute__((ext_vector_type(4))) float;
using i32x4  = __attribute__((ext_vector_type(4))) int;

__device__ inline int q8(float f, float s) {
  float v = fminf(fmaxf(f * s, -127.0f), 127.0f);
  return (int)rintf(v);
}

// ---------------------------------------------------------------- prep
// Fragment-major i8 codebook for 16x16x64: group g = codes [g*16,g*16+16),
// k-frag kk covers k=[kk*64,kk*64+64). Lane l holds code g*16+(l&15),
// k = kk*64+(l>>4)*16..+16 (16 B). Frag f = g*4+kk is 1 KB contiguous.
__global__ __launch_bounds__(64) void prep_kernel(const float* __restrict__ ew,
                                                  char* __restrict__ ebf,
                                                  int* __restrict__ ct_int) {
  const int c = blockIdx.x;
  const int t = threadIdx.x;            // handles k = 4t .. 4t+3
  f32x4 v = *((const f32x4*)(ew + (size_t)c * DIM) + t);
  int p = (q8(v[0], SE) & 255) | ((q8(v[1], SE) & 255) << 8)
        | ((q8(v[2], SE) & 255) << 16) | ((q8(v[3], SE) & 255) << 24);
  int frag = (c >> 4) * 4 + (t >> 4);           // kk = t>>4
  int lhi  = (t >> 2) & 3;                      // k-sub within frag
  int addr = frag * 1024 + (lhi * 16 + (c & 15)) * 16 + (t & 3) * 4;
  *(int*)(ebf + addr) = p;
  float ss = v[0] * v[0] + v[1] * v[1] + v[2] * v[2] + v[3] * v[3];
#pragma unroll
  for (int off = 32; off > 0; off >>= 1) ss += __shfl_xor(ss, off, 64);
  if (t == 0) ct_int[c] = (int)rintf(-0.5f * ss * (SX * SE));
}

// ---------------------------------------------------------------- argmin
// One 16-code group: 8 MFMA (i8, K=64) with C-init = ct, then
// key = (acc<<10) + (1023-code) folded by integer max.
#define COMPUTE16(B, CT, GG)                                                    \
  {                                                                             \
    i32x4 acc[2];                                                               \
    acc[0] = i32x4{CT, CT, CT, CT};                                             \
    acc[1] = i32x4{CT, CT, CT, CT};                                             \
    _Pragma("unroll")                                                           \
    for (int kk = 0; kk < 4; ++kk) {                                            \
      acc[0] = __builtin_amdgcn_mfma_i32_16x16x64_i8(a[0][kk], B[kk], acc[0], 0, 0, 0); \
      acc[1] = __builtin_amdgcn_mfma_i32_16x16x64_i8(a[1][kk], B[kk], acc[1], 0, 0, 0); \
    }                                                                           \
    int tr = 1023 - ((GG) * 16 + l15);                                          \
    _Pragma("unroll")                                                           \
    for (int mi = 0; mi < 2; ++mi)                                              \
      _Pragma("unroll")                                                         \
      for (int r = 0; r < 4; ++r) {                                             \
        int key = (int)(((unsigned)acc[mi][r]) << 10) + tr;                     \
        bk[mi][r] = key > bk[mi][r] ? key : bk[mi][r];                          \
      }                                                                         \
  }

__global__ __launch_bounds__(64, 1) void argmin_kernel(const float* __restrict__ x,
                                                       const char* __restrict__ ebf,
                                                       const int* __restrict__ ct_int,
                                                       int* __restrict__ keys,
                                                       float* __restrict__ partials_x2) {
  const int lane = threadIdx.x;
  const int l15  = lane & 15;
  const int lhi  = lane >> 4;            // 0..3
  const int half = blockIdx.x & 1;       // codebook half
  const int row0 = (blockIdx.x >> 1) * 32;
  const int gbase = half * 32;           // 32 groups = 512 codes per block

  // ---- X -> registers (i8 frags, same lane->k map as B), x2a in fp32 ----
  float x2a = 0.0f;
  i32x4 a[2][4];
#pragma unroll
  for (int mi = 0; mi < 2; ++mi) {
    const float* xr = x + (size_t)(row0 + mi * 16 + l15) * DIM;
#pragma unroll
    for (int kk = 0; kk < 4; ++kk) {
      const float* ks = xr + kk * 64 + lhi * 16;
      i32x4 pk;
#pragma unroll
      for (int j = 0; j < 4; ++j) {
        f32x4 v = *(const f32x4*)(ks + j * 4);
        x2a += v[0] * v[0] + v[1] * v[1] + v[2] * v[2] + v[3] * v[3];
        pk[j] = (q8(v[0], SX) & 255) | ((q8(v[1], SX) & 255) << 8)
              | ((q8(v[2], SX) & 255) << 16) | ((q8(v[3], SX) & 255) << 24);
      }
      a[mi][kk] = pk;
    }
  }

  int bk[2][4];
#pragma unroll
  for (int i = 0; i < 2; ++i)
#pragma unroll
    for (int r = 0; r < 4; ++r) bk[i][r] = (int)0x80000000;

  // ---- B register ping-pong over THIS BLOCK'S 32 groups ----
  const i32x4* bfr = (const i32x4*)ebf;    // frag f, lane l -> bfr[f*64 + l]
  i32x4 bA[4], bB[4];
  int   ctA, ctB;
#pragma unroll
  for (int f = 0; f < 4; ++f) bA[f] = bfr[((gbase) * 4 + f) * 64 + lane];
  ctA = ct_int[gbase * 16 + l15];

  for (int g = 0; g < 32; g += 2) {
    // prefetch group g+1 while computing g
#pragma unroll
    for (int f = 0; f < 4; ++f) bB[f] = bfr[((gbase + g + 1) * 4 + f) * 64 + lane];
    ctB = ct_int[(gbase + g + 1) * 16 + l15];
    COMPUTE16(bA, ctA, gbase + g);
    // prefetch group g+2 while computing g+1
    if (g + 2 < 32) {
#pragma unroll
      for (int f = 0; f < 4; ++f) bA[f] = bfr[((gbase + g + 2) * 4 + f) * 64 + lane];
      ctA = ct_int[(gbase + g + 2) * 16 + l15];
    }
    COMPUTE16(bB, ctB, gbase + g + 1);
  }

  // ---- reduce int keys over the 16 code-lanes; write per-row half-key ----
#pragma unroll
  for (int mi = 0; mi < 2; ++mi)
#pragma unroll
    for (int r = 0; r < 4; ++r) {
      int v = bk[mi][r];
#pragma unroll
      for (int off = 1; off < 16; off <<= 1) {
        int o = __shfl_xor(v, off, 64);
        v = o > v ? o : v;
      }
      bk[mi][r] = v;
    }
  if (l15 == 0) {                        // lanes 0,16,32,48: rows mi*16 + lhi*4 + r
#pragma unroll
    for (int mi = 0; mi < 2; ++mi)
#pragma unroll
      for (int r = 0; r < 4; ++r)
        keys[(size_t)(row0 + mi * 16 + lhi * 4 + r) * 2 + half] = bk[mi][r];
  }

  if (half == 0) {                       // one x2 partial per row-group
    float red = x2a;
#pragma unroll
    for (int off = 1; off < 64; off <<= 1) red += __shfl_xor(red, off, 64);
    if (lane == 0) partials_x2[blockIdx.x >> 1] = red;
  }
}

// ---------------------------------------------------------------- gather (merge + stream)
// One wave per 8 consecutive rows. Merge half-keys (one int max), derive
// code + winning sv, gather 1 KB ew row, nt-store; write sv partial.
__global__ __launch_bounds__(256) void gather_kernel(const float* __restrict__ ew,
                                                     const int* __restrict__ keys,
                                                     float* __restrict__ qout,
                                                     float* __restrict__ partials_sv) {
  const int w    = (blockIdx.x * 256 + threadIdx.x) >> 6;   // 0..8191
  const int lane = threadIdx.x & 63;
  const int base = w * 8;
  const float inv_s = 1.0f / (SX * SE);
  int c[8];
  float svs = 0.0f;
#pragma unroll
  for (int i = 0; i < 8; ++i) {
    int k0 = keys[(size_t)(base + i) * 2];
    int k1 = keys[(size_t)(base + i) * 2 + 1];
    int k  = k0 > k1 ? k0 : k1;
    c[i] = 1023 - (k & 1023);
    svs += (float)(k >> 10) * inv_s;     // sv = x.e - 0.5||e||^2
  }
  if (lane == 0) partials_sv[w] = svs;
#pragma unroll
  for (int i = 0; i < 8; ++i) {
    f32x4 v = *((const f32x4*)(ew + (size_t)c[i] * DIM) + lane);
    __builtin_nontemporal_store(v, ((f32x4*)(qout + (size_t)(base + i) * DIM)) + lane);
  }
}

// ---------------------------------------------------------------- final loss
__global__ __launch_bounds__(256) void loss_kernel(const float* __restrict__ partials_x2,
                                                   const float* __restrict__ partials_sv,
                                                   float* __restrict__ out_loss) {
  __shared__ double red[256];
  double a = 0.0;
  for (int i = threadIdx.x; i < 2048; i += 256) a += (double)partials_x2[i];
  for (int i = threadIdx.x; i < 8192; i += 256) a -= 2.0 * (double)partials_sv[i];
  red[threadIdx.x] = a;
  __syncthreads();
  for (int s = 128; s > 0; s >>= 1) {
    if (threadIdx.x < s) red[threadIdx.x] += red[threadIdx.x + s];
    __syncthreads();
  }
  if (threadIdx.x == 0) out_loss[0] = (float)(1.25 * red[0] / 16777216.0);
}

// ---------------------------------------------------------------- launch
extern "C" void kernel_launch(void* const* d_in, const int* in_sizes, int n_in,
                              void* d_out, int out_size, void* d_ws, size_t ws_size,
                              hipStream_t stream) {
  const float* x  = (const float*)d_in[0];   // inputs [65536,256]
  const float* ew = (const float*)d_in[1];   // embed  [1024,256]
  float* out = (float*)d_out;

  char* ws = (char*)d_ws;
  char*  ebf         = ws;                            // 256 KiB (fragment-major i8)
  int*   ct_int      = (int*)(ws + 262144);           // 4 KiB
  float* partials_x2 = (float*)(ws + 266240);         // 8 KiB (2048 row-groups)
  int*   keys        = (int*)(ws + 274432);           // 512 KiB (65536 x 2)
  float* partials_sv = (float*)(ws + 798720);         // 32 KiB (8192 waves)

  prep_kernel<<<NCODES, 64, 0, stream>>>(ew, ebf, ct_int);
  argmin_kernel<<<M_ROWS / 32 * 2, 64, 0, stream>>>(x, ebf, ct_int, keys, partials_x2);
  gather_kernel<<<2048, 256, 0, stream>>>(ew, keys, out, partials_sv);
  loss_kernel<<<1, 256, 0, stream>>>(partials_x2, partials_sv, out + 16777216);
}

// Round 14
// 62.033 us; speedup vs baseline: 1.3408x; 1.1943x over previous
//
#include <hip/hip_runtime.h>
#include <hip/hip_bf16.h>

// Quantizer (VQ-VAE): inputs [32,2048,256] f32, embed [1024,256] f32.
// out = (quantized [32,2048,256] f32, latent_loss scalar f32) concatenated.
//
// Round-14: EXACT round-11 shape (best argmin: 43.4us, VGPR 112, grid 2048,
// full codebook per wave, depth-1 ping-pong) + L2-THRASH FIX:
//   x loads are NONTEMPORAL (evict-first) so the 64MB x stream no longer
//   evicts the 256KB i8 codebook from the 4MB/XCD L2. Round-11's ~680cyc
//   per-group stall == L3/HBM latency on B-loads == codebook eviction.
//   First B group is loaded BEFORE the x prologue to warm the lines.
//
//   prep_kernel   : embed -> i8 FRAGMENT-MAJOR pack + ct_int per code
//   argmin_kernel : 32 rows/wave; A i8 in regs a[2][4]; B depth-1 ping-pong;
//                   ct in MFMA C-init; int-key argmin (exact, low-index ties)
//   gather_kernel : q[r] = ew[codes[r]] (1 KB contiguous nt-store per row)
//   loss_kernel   : 1.25 * [sum(x^2) - 2*sum(sv)] / (N*D)

#define DIM     256
#define M_ROWS  65536
#define NCODES  1024
#define SX      28.0f
#define SE      130048.0f        // 1024 * 127

using f32x4  = __attribute__((ext_vector_type(4))) float;
using i32x4  = __attribute__((ext_vector_type(4))) int;

__device__ inline int q8(float f, float s) {
  float v = fminf(fmaxf(f * s, -127.0f), 127.0f);
  return (int)rintf(v);
}

// ---------------------------------------------------------------- prep
// Fragment-major i8 codebook for 16x16x64: group g = codes [g*16,g*16+16),
// k-frag kk covers k=[kk*64,kk*64+64). Lane l holds code g*16+(l&15),
// k = kk*64+(l>>4)*16..+16 (16 B). Frag f = g*4+kk is 1 KB contiguous.
__global__ __launch_bounds__(64) void prep_kernel(const float* __restrict__ ew,
                                                  char* __restrict__ ebf,
                                                  int* __restrict__ ct_int) {
  const int c = blockIdx.x;
  const int t = threadIdx.x;            // handles k = 4t .. 4t+3
  f32x4 v = *((const f32x4*)(ew + (size_t)c * DIM) + t);
  int p = (q8(v[0], SE) & 255) | ((q8(v[1], SE) & 255) << 8)
        | ((q8(v[2], SE) & 255) << 16) | ((q8(v[3], SE) & 255) << 24);
  int frag = (c >> 4) * 4 + (t >> 4);           // kk = t>>4
  int lhi  = (t >> 2) & 3;                      // k-sub within frag
  int addr = frag * 1024 + (lhi * 16 + (c & 15)) * 16 + (t & 3) * 4;
  *(int*)(ebf + addr) = p;
  float ss = v[0] * v[0] + v[1] * v[1] + v[2] * v[2] + v[3] * v[3];
#pragma unroll
  for (int off = 32; off > 0; off >>= 1) ss += __shfl_xor(ss, off, 64);
  if (t == 0) ct_int[c] = (int)rintf(-0.5f * ss * (SX * SE));
}

// ---------------------------------------------------------------- argmin
// One 16-code group: 8 MFMA (i8, K=64) with C-init = ct, then
// key = (acc<<10) + (1023-code) folded by integer max.
#define COMPUTE16(B, CT, GG)                                                    \
  {                                                                             \
    i32x4 acc[2];                                                               \
    acc[0] = i32x4{CT, CT, CT, CT};                                             \
    acc[1] = i32x4{CT, CT, CT, CT};                                             \
    _Pragma("unroll")                                                           \
    for (int kk = 0; kk < 4; ++kk) {                                            \
      acc[0] = __builtin_amdgcn_mfma_i32_16x16x64_i8(a[0][kk], B[kk], acc[0], 0, 0, 0); \
      acc[1] = __builtin_amdgcn_mfma_i32_16x16x64_i8(a[1][kk], B[kk], acc[1], 0, 0, 0); \
    }                                                                           \
    int tr = 1023 - ((GG) * 16 + l15);                                          \
    _Pragma("unroll")                                                           \
    for (int mi = 0; mi < 2; ++mi)                                              \
      _Pragma("unroll")                                                         \
      for (int r = 0; r < 4; ++r) {                                             \
        int key = (int)(((unsigned)acc[mi][r]) << 10) + tr;                     \
        bk[mi][r] = key > bk[mi][r] ? key : bk[mi][r];                          \
      }                                                                         \
  }

__global__ __launch_bounds__(64, 1) void argmin_kernel(const float* __restrict__ x,
                                                       const char* __restrict__ ebf,
                                                       const int* __restrict__ ct_int,
                                                       int* __restrict__ out_codes,
                                                       float* __restrict__ partials) {
  const int lane = threadIdx.x;
  const int l15  = lane & 15;
  const int lhi  = lane >> 4;            // 0..3
  const int row0 = blockIdx.x * 32;

  const i32x4* bfr = (const i32x4*)ebf;  // frag f, lane l -> bfr[f*64 + l]

  // ---- issue group-0 B loads FIRST (warm codebook lines under x loads) ----
  i32x4 bA[4], bB[4];
  int   ctA, ctB;
#pragma unroll
  for (int f = 0; f < 4; ++f) bA[f] = bfr[f * 64 + lane];
  ctA = ct_int[l15];

  // ---- X -> registers via NONTEMPORAL loads (don't evict codebook in L2) ----
  float x2a = 0.0f;
  i32x4 a[2][4];
#pragma unroll
  for (int mi = 0; mi < 2; ++mi) {
    const float* xr = x + (size_t)(row0 + mi * 16 + l15) * DIM;
#pragma unroll
    for (int kk = 0; kk < 4; ++kk) {
      const float* ks = xr + kk * 64 + lhi * 16;
      i32x4 pk;
#pragma unroll
      for (int j = 0; j < 4; ++j) {
        f32x4 v = __builtin_nontemporal_load((const f32x4*)(ks + j * 4));
        x2a += v[0] * v[0] + v[1] * v[1] + v[2] * v[2] + v[3] * v[3];
        pk[j] = (q8(v[0], SX) & 255) | ((q8(v[1], SX) & 255) << 8)
              | ((q8(v[2], SX) & 255) << 16) | ((q8(v[3], SX) & 255) << 24);
      }
      a[mi][kk] = pk;
    }
  }

  int bk[2][4];
#pragma unroll
  for (int i = 0; i < 2; ++i)
#pragma unroll
    for (int r = 0; r < 4; ++r) bk[i][r] = (int)0x80000000;

  // ---- B register ping-pong: one 16-code group (4 frags, 4 KB) ahead ----
  for (int g = 0; g < 64; g += 2) {
    // prefetch group g+1 while computing g
#pragma unroll
    for (int f = 0; f < 4; ++f) bB[f] = bfr[((g + 1) * 4 + f) * 64 + lane];
    ctB = ct_int[(g + 1) * 16 + l15];
    COMPUTE16(bA, ctA, g);
    // prefetch group g+2 while computing g+1
    if (g + 2 < 64) {
#pragma unroll
      for (int f = 0; f < 4; ++f) bA[f] = bfr[((g + 2) * 4 + f) * 64 + lane];
      ctA = ct_int[(g + 2) * 16 + l15];
    }
    COMPUTE16(bB, ctB, g + 1);
  }

  // ---- reduce int keys over the 16 code-lanes ----
#pragma unroll
  for (int mi = 0; mi < 2; ++mi)
#pragma unroll
    for (int r = 0; r < 4; ++r) {
      int v = bk[mi][r];
#pragma unroll
      for (int off = 1; off < 16; off <<= 1) {
        int o = __shfl_xor(v, off, 64);
        v = o > v ? o : v;
      }
      bk[mi][r] = v;
    }

  float svtot = 0.0f;
  if (l15 == 0) {                        // lanes 0,16,32,48: rows mi*16 + lhi*4 + r
    const float inv_s = 1.0f / (SX * SE);
#pragma unroll
    for (int mi = 0; mi < 2; ++mi)
#pragma unroll
      for (int r = 0; r < 4; ++r) {
        int key = bk[mi][r];
        out_codes[row0 + mi * 16 + lhi * 4 + r] = 1023 - (key & 1023);
        svtot += (float)(key >> 10) * inv_s;   // sv = x.e - 0.5||e||^2
      }
  }
  float red = x2a - 2.0f * svtot;        // partial: sum x^2 - 2*sum sv
#pragma unroll
  for (int off = 1; off < 64; off <<= 1) red += __shfl_xor(red, off, 64);
  if (lane == 0) partials[blockIdx.x] = red;
}

// ---------------------------------------------------------------- gather (pure stream)
// One wave per 8 consecutive rows; each row = 1 KB contiguous (64 lanes x 16 B).
__global__ __launch_bounds__(256) void gather_kernel(const float* __restrict__ ew,
                                                     const int* __restrict__ codes,
                                                     float* __restrict__ qout) {
  const int w    = (blockIdx.x * 256 + threadIdx.x) >> 6;   // 0..8191
  const int lane = threadIdx.x & 63;
  const int base = w * 8;
  int c[8];
#pragma unroll
  for (int i = 0; i < 8; ++i) c[i] = codes[base + i];
#pragma unroll
  for (int i = 0; i < 8; ++i) {
    f32x4 v = *((const f32x4*)(ew + (size_t)c[i] * DIM) + lane);
    __builtin_nontemporal_store(v, ((f32x4*)(qout + (size_t)(base + i) * DIM)) + lane);
  }
}

// ---------------------------------------------------------------- final loss
__global__ __launch_bounds__(256) void loss_kernel(const float* __restrict__ partials,
                                                   float* __restrict__ out_loss) {
  __shared__ double red[256];
  double a = 0.0;
  for (int i = threadIdx.x; i < 2048; i += 256) a += (double)partials[i];
  red[threadIdx.x] = a;
  __syncthreads();
  for (int s = 128; s > 0; s >>= 1) {
    if (threadIdx.x < s) red[threadIdx.x] += red[threadIdx.x + s];
    __syncthreads();
  }
  if (threadIdx.x == 0) out_loss[0] = (float)(1.25 * red[0] / 16777216.0);
}

// ---------------------------------------------------------------- launch
extern "C" void kernel_launch(void* const* d_in, const int* in_sizes, int n_in,
                              void* d_out, int out_size, void* d_ws, size_t ws_size,
                              hipStream_t stream) {
  const float* x  = (const float*)d_in[0];   // inputs [65536,256]
  const float* ew = (const float*)d_in[1];   // embed  [1024,256]
  float* out = (float*)d_out;

  char* ws = (char*)d_ws;
  char*  ebf      = ws;                               // 256 KiB (fragment-major i8)
  int*   ct_int   = (int*)(ws + 262144);              // 4 KiB
  float* partials = (float*)(ws + 266240);            // 8 KiB (2048 waves)
  int*   codes    = (int*)(ws + 274432);              // 256 KiB

  prep_kernel<<<NCODES, 64, 0, stream>>>(ew, ebf, ct_int);
  argmin_kernel<<<M_ROWS / 32, 64, 0, stream>>>(x, ebf, ct_int, codes, partials);
  gather_kernel<<<2048, 256, 0, stream>>>(ew, codes, out);
  loss_kernel<<<1, 256, 0, stream>>>(partials, out + 16777216);
}